// Round 6
// baseline (479.515 us; speedup 1.0000x reference)
//
#include <hip/hip_runtime.h>
#include <hip/hip_bf16.h>

// Qwen2 attention block: qkv = hs@Wqkv+b; rope(q,k); causal GQA attention; out = attn@Wo
// T=2048 D=3584 HQ=28 HKV=4 DH=128. All matmuls in bf16 MFMA (16x16x32), fp32 accum.
// R4 (accuracy): RNE P-pack, rounded-P denom, fp32 split-KV partials -> absmax 0.031.
// R6 (determinism): 1-barrier dbuf skeleton -> PASS. R7 FAILED: no staging (VGPR-bound
//     direct loads serialize). R8: K+V staged dbuf, 128q x 8 waves -> 473us total;
//     attn out of top-5. GEMMs now dominate: 111us each, MfmaUtil 25%, ~2400 cy/iter
//     (vmcnt(0)-before-barrier drain paid 112x/block; all waves co-resident).
// R9: gemm_bt BK 32->64 (halves drain events, 56 iters) + T2 XOR block-swizzle
//     (BK=64 rows would be 16-way bank degenerate; swizzle -> uniform 32-bank) +
//     T1 XCD-aware block remap (grids 576,448 %8==0, bijective; A-panel L2 locality
//     shortens the drain itself). K-order unchanged -> bit-identical output.

#define T_SEQ 2048
#define D_MODEL 3584
#define HQ 28
#define HKV 4
#define GQA 7
#define DH 128
#define NQKV 4608   // (HQ+2*HKV)*DH
#define KVD 512     // HKV*DH

typedef unsigned short u16;
typedef __attribute__((ext_vector_type(8))) short short8;   // 8 bf16 (4 VGPRs)
typedef __attribute__((ext_vector_type(4))) float floatx4;

__device__ __forceinline__ u16 f2b(float x) {               // fp32 -> bf16 RNE
    unsigned u = __float_as_uint(x);
    return (u16)((u + 0x7fffu + ((u >> 16) & 1u)) >> 16);
}
__device__ __forceinline__ float b2f(u16 x) {
    return __uint_as_float((unsigned)x << 16);
}
__device__ __forceinline__ void gl_lds16(const u16* g, u16* l) {
    // async global->LDS, 16B/lane; LDS dest = wave-uniform base + lane*16
    __builtin_amdgcn_global_load_lds((const __attribute__((address_space(1))) void*)g,
                                     (__attribute__((address_space(3))) void*)l, 16, 0, 0);
}

// Compact split-KV partial row index. Chunk c covers kv [512c,512c+512); partials are
// only needed for rows with >=2 chunks: t >= 512*max(c,1). Row counts {1536,1536,1024,512}.
__device__ __forceinline__ long part_row(int c, int h, int t) {
    int tmin = (c == 0) ? 512 : (c << 9);
    int rows = 2048 - tmin;
    int rb = (c <= 1) ? (c * 1536) : (c == 2 ? 3072 : 4096);   // row prefix sum
    return (long)rb * HQ + (long)h * rows + (t - tmin);
}

// ---------------- fp32 -> bf16 straight convert ----------------
__global__ void cvt_kernel(const float* __restrict__ in, u16* __restrict__ out, int n) {
    int i = (blockIdx.x * blockDim.x + threadIdx.x) * 4;
    if (i + 3 < n) {
        float4 v = *(const float4*)(in + i);
        u16 o0 = f2b(v.x), o1 = f2b(v.y), o2 = f2b(v.z), o3 = f2b(v.w);
        uint2 pk;
        pk.x = (unsigned)o0 | ((unsigned)o1 << 16);
        pk.y = (unsigned)o2 | ((unsigned)o3 << 16);
        *(uint2*)(out + i) = pk;
    }
}

// ---------------- fp32 (R x C) -> bf16 transposed (C x R) ----------------
__global__ void transpose_cvt(const float* __restrict__ in, u16* __restrict__ out, int R, int C) {
    __shared__ u16 tile[32][33];
    int c0 = blockIdx.x * 32, r0 = blockIdx.y * 32;
    int tx = threadIdx.x, ty = threadIdx.y;   // (32,8)
#pragma unroll
    for (int i = 0; i < 32; i += 8)
        tile[ty + i][tx] = f2b(in[(long)(r0 + ty + i) * C + c0 + tx]);
    __syncthreads();
#pragma unroll
    for (int i = 0; i < 32; i += 8)
        out[(long)(c0 + ty + i) * R + r0 + tx] = tile[tx][ty + i];
}

// ---------------- bf16 GEMM: C = A(MxK) * Bt(NxK)^T + bias, fp32 out ----------------
// 128x128 tile, BK=64, XOR-swizzled LDS blocks, double-buffered, 1 barrier/iter,
// XCD-aware block remap (requires gridDim.x*gridDim.y % 8 == 0).
__global__ __launch_bounds__(256) void gemm_bt(
    const u16* __restrict__ A, const u16* __restrict__ Bt,
    float* __restrict__ C, const float* __restrict__ bias,
    int M, int N, int K)
{
    __shared__ __align__(16) u16 As[2][128 * 64];
    __shared__ __align__(16) u16 Bs[2][128 * 64];
    const int tid = threadIdx.x;
    const int lane = tid & 63, wave = tid >> 6;
    const int quad = lane >> 4, l16 = lane & 15;
    const int wm = (wave >> 1) * 64, wn = (wave & 1) * 64;
    // T1: XCD-aware bijective remap (nwg % 8 == 0 for both launches: 576, 448)
    const int nwg = gridDim.x * gridDim.y;
    const int bid = blockIdx.y * gridDim.x + blockIdx.x;
    const int wid = (bid & 7) * (nwg >> 3) + (bid >> 3);
    const int m0 = (wid / gridDim.x) * 128, n0 = (wid % gridDim.x) * 128;

    floatx4 acc[4][4] = {};

    // T2 swizzle: LDS[row][blk] holds global[row][blk ^ (row&7)] (8 x 16B blocks/row)
    auto stage = [&](int k0, int b) {
#pragma unroll
        for (int j = 0; j < 4; j++) {
            int r = wave * 32 + j * 8 + (lane >> 3);          // 8 rows per instr
            int gcb = (lane & 7) ^ (lane >> 3);               // pre-swizzled source block
            const u16* ga = A + (long)(m0 + r) * K + k0 + gcb * 8;
            const u16* gb = Bt + (long)(n0 + r) * K + k0 + gcb * 8;
            gl_lds16(ga, &As[b][(wave * 32 + j * 8) * 64]);
            gl_lds16(gb, &Bs[b][(wave * 32 + j * 8) * 64]);
        }
    };

    stage(0, 0);
    int it = 0;
    for (int k0 = 0; k0 < K; k0 += 64, it++) {
        int b = it & 1;
        __syncthreads();
        if (k0 + 64 < K) stage(k0 + 64, b ^ 1);
#pragma unroll
        for (int kk = 0; kk < 2; kk++) {                      // same K order as BK=32 -> bit-identical
            short8 af[4], bfr[4];
            int sb = ((kk << 2) + quad) ^ (l16 & 7);          // swizzled 16B block
#pragma unroll
            for (int i = 0; i < 4; i++)
                af[i] = *(const short8*)(&As[b][0] + (wm + i * 16 + l16) * 64 + sb * 8);
#pragma unroll
            for (int i = 0; i < 4; i++)
                bfr[i] = *(const short8*)(&Bs[b][0] + (wn + i * 16 + l16) * 64 + sb * 8);
#pragma unroll
            for (int mi = 0; mi < 4; mi++)
#pragma unroll
                for (int ni = 0; ni < 4; ni++)
                    acc[mi][ni] = __builtin_amdgcn_mfma_f32_16x16x32_bf16(af[mi], bfr[ni], acc[mi][ni], 0, 0, 0);
        }
    }

#pragma unroll
    for (int mi = 0; mi < 4; mi++) {
        int row = m0 + wm + mi * 16 + quad * 4;
#pragma unroll
        for (int ni = 0; ni < 4; ni++) {
            int col = n0 + wn + ni * 16 + l16;
            float b = bias ? bias[col] : 0.0f;
#pragma unroll
            for (int r = 0; r < 4; r++)
                C[(long)(row + r) * N + col] = acc[mi][ni][r] + b;
        }
    }
}

// ---------------- RoPE + split; Q pre-scaled by (1/sqrt(DH))*log2(e) for exp2 softmax ----------------
__global__ void rope_split(const float* __restrict__ qkv, const int* __restrict__ pos,
                           u16* __restrict__ Qb, u16* __restrict__ Kb, u16* __restrict__ VbT)
{
    int t = blockIdx.x, h = blockIdx.y, j = threadIdx.x;  // j in [0,64)
    const float* row = qkv + (long)t * NQKV + h * DH;
    if (h < HQ + HKV) {
        float x1 = row[j], x2 = row[j + 64];
        float inv = exp2f(-0.311430758889f * (float)j);   // theta^(-j/64)
        float ang = (float)pos[t] * inv;
        float c = cosf(ang), s = sinf(ang);
        float o1 = x1 * c - x2 * s;
        float o2 = x2 * c + x1 * s;
        if (h < HQ) {
            const float scale = 0.08838834764831845f * 1.4426950408889634f;  // 1/sqrt(128)*log2e
            u16* o = Qb + (long)t * D_MODEL + h * DH;
            o[j] = f2b(o1 * scale); o[j + 64] = f2b(o2 * scale);
        } else {
            u16* o = Kb + (long)t * KVD + (h - HQ) * DH;
            o[j] = f2b(o1); o[j + 64] = f2b(o2);
        }
    } else {
        int hv = h - HQ - HKV;
        VbT[(long)(hv * DH + j) * T_SEQ + t] = f2b(row[j]);
        VbT[(long)(hv * DH + j + 64) * T_SEQ + t] = f2b(row[j + 64]);
    }
}

// ---------------- flash attention, split-KV, S^T form. Block = 128 q x 512 kv chunk. ----------------
// R8: K+V double-buffered via global_load_lds (no VGPR cost), ONE barrier/iter — exact
// gemm_bt skeleton (determinism-proven). 8 waves/block, 80KB LDS -> 2 blocks/CU.
__global__ __launch_bounds__(512, 4) void attn_kernel(
    const u16* __restrict__ Qb, const u16* __restrict__ Kb, const u16* __restrict__ VbT,
    float* __restrict__ Opf, float* __restrict__ mlbuf, u16* __restrict__ attnb)
{
    __shared__ __align__(16) u16 smem[40960];  // Kt[2][64*128] | Vt[2][128*64] | Ps[8][16*64] = 80KB
    u16* Ps = smem + 32768;
    // decode (qb, chunk) for 128-row q tiles: tier g=qb>>2 has g+1 chunks of 512 kv
    int bx = blockIdx.x, qb, ch;
    if (bx < 4)       { qb = bx;               ch = 0; }
    else if (bx < 12) { int j = bx - 4;  qb = 4  + (j >> 1); ch = j & 1; }
    else if (bx < 24) { int j = bx - 12; qb = 8  + j / 3;    ch = j % 3; }
    else              { int j = bx - 24; qb = 12 + (j >> 2); ch = j & 3; }
    const int h = blockIdx.y;
    const int kvh = h / GQA;
    const int q0 = qb * 128;
    const int c_lo = ch * 512;
    const int c_hi = min(c_lo + 512, q0 + 128);
    const int n_it = (c_hi - c_lo) >> 6;
    const int tid = threadIdx.x;
    const int wave = tid >> 6, lane = tid & 63;   // wave 0..7
    const int quad = lane >> 4, l16 = lane & 15;
    const int h7 = l16 & 7;
    const int qrow = q0 + wave * 16;

    auto stageK = [&](int itx, int b) {           // Kt[b]: [kv=64][d=128], XOR-swizzled 16B blocks
        int c0 = c_lo + (itx << 6);
        u16* kt = smem + b * 8192;
#pragma unroll
        for (int j = 0; j < 2; j++) {             // 4 rows x 256B per instr
            int row = wave * 8 + j * 4 + (lane >> 4);
            int gcb = ((lane & 15) & 8) | (((lane & 15) & 7) ^ (row & 7));
            gl_lds16(Kb + (long)(c0 + row) * KVD + kvh * DH + gcb * 8,
                     kt + (wave * 8 + j * 4) * 128);
        }
    };
    auto stageV = [&](int itx, int b) {           // Vt[b]: [d=128][t=64], XOR-swizzled
        int c0 = c_lo + (itx << 6);
        u16* vt = smem + 16384 + b * 8192;
#pragma unroll
        for (int j = 0; j < 2; j++) {             // 8 rows x 128B per instr
            int row = wave * 16 + j * 8 + (lane >> 3);
            int gcb = (lane & 7) ^ (row & 7);
            gl_lds16(VbT + (long)(kvh * DH + row) * T_SEQ + c0 + gcb * 8,
                     vt + (wave * 16 + j * 8) * 64);
        }
    };

    // Q as B-operand: B[n=q=l16][k=d], b128 loads
    short8 qf[4];
    const u16* qptr = Qb + (long)(qrow + l16) * D_MODEL + h * DH;
#pragma unroll
    for (int kc = 0; kc < 4; kc++)
        qf[kc] = *(const short8*)(qptr + kc * 32 + quad * 8);

    floatx4 acc_o[8] = {};                 // O^T[d = di*16+quad*4+r][q = l16]
    float m_run = -3e38f, l_run = 0.f;     // per-lane: one q row (log2 domain)
    u16* pw = Ps + wave * (16 * 64);

    stageK(0, 0);
    stageV(0, 0);

    for (int itx = 0; itx < n_it; itx++) {
        int c0 = c_lo + (itx << 6);
        int b = itx & 1;
        __syncthreads();                   // Kt[b],Vt[b] staged (own-wave DMA drained here)
        if (itx + 1 < n_it) { stageK(itx + 1, b ^ 1); stageV(itx + 1, b ^ 1); }
        u16* kt = smem + b * 8192;
        u16* vt = smem + 16384 + b * 8192;
        // ---- S^T = K Q^T: lane owns q=l16, kv = mi*16+quad*4+r ----
        floatx4 s[4] = {};
#pragma unroll
        for (int kc = 0; kc < 4; kc++) {
            short8 kf[4];
            int cs = (((kc * 4 + quad) & 8)) | (((kc * 4 + quad) & 7) ^ h7);
#pragma unroll
            for (int mi = 0; mi < 4; mi++)
                kf[mi] = *(const short8*)(kt + (mi * 16 + l16) * 128 + cs * 8);
#pragma unroll
            for (int mi = 0; mi < 4; mi++)
                s[mi] = __builtin_amdgcn_mfma_f32_16x16x32_bf16(kf[mi], qf[kc], s[mi], 0, 0, 0);
        }
        // ---- causal mask (wave-uniform branch; only diagonal-crossing tiles) ----
        if (c0 + 63 > qrow) {
            int qg = qrow + l16;
#pragma unroll
            for (int mi = 0; mi < 4; mi++)
#pragma unroll
                for (int r = 0; r < 4; r++)
                    if (c0 + mi * 16 + quad * 4 + r > qg) s[mi][r] = -1e30f;
        }
        // ---- per-lane online softmax (in-lane 16 + 2 cross-quad shuffles) ----
        float tm = s[0][0];
#pragma unroll
        for (int mi = 0; mi < 4; mi++)
#pragma unroll
            for (int r = 0; r < 4; r++) tm = fmaxf(tm, s[mi][r]);
        tm = fmaxf(tm, __shfl_xor(tm, 16));
        tm = fmaxf(tm, __shfl_xor(tm, 32));
        float nm = fmaxf(m_run, tm);
        float alpha = exp2f(m_run - nm);
        m_run = nm;
#pragma unroll
        for (int mi = 0; mi < 4; mi++)
#pragma unroll
            for (int r = 0; r < 4; r++)
                s[mi][r] = exp2f(s[mi][r] - nm);
        // ---- pack P to bf16 with RNE; denominator from the ROUNDED values so the
        //      softmax normalization is exact w.r.t. what the PV MFMA actually sums ----
        float rs = 0.f;
#pragma unroll
        for (int mi = 0; mi < 4; mi++) {
            int cb = (mi * 2 + (quad >> 1)) ^ h7;
#pragma unroll
            for (int c = 0; c < 2; c++) {
                u16 ra = f2b(s[mi][2 * c]), rb2 = f2b(s[mi][2 * c + 1]);
                rs += b2f(ra) + b2f(rb2);
                *(unsigned*)(pw + l16 * 64 + cb * 8 + (quad & 1) * 4 + c * 2) =
                    (unsigned)ra | ((unsigned)rb2 << 16);
            }
        }
        rs += __shfl_xor(rs, 16);
        rs += __shfl_xor(rs, 32);
        l_run = l_run * alpha + rs;
        asm volatile("" ::: "memory");     // compiler fence: Ps stores before Ps loads (same wave)
#pragma unroll
        for (int di = 0; di < 8; di++)
#pragma unroll
            for (int r = 0; r < 4; r++)
                acc_o[di][r] *= alpha;
        // ---- O^T += V^T P: A=V^T from Vt[b], B=P from wave-private Ps ----
#pragma unroll
        for (int kc = 0; kc < 2; kc++) {
            uint4 pv = *(const uint4*)(pw + l16 * 64 + (((kc * 4 + quad) ^ h7) << 3));
            short8 pf = __builtin_bit_cast(short8, pv);
            int csv = (kc * 4 + quad) ^ h7;
#pragma unroll
            for (int di = 0; di < 8; di++) {
                short8 vf = *(const short8*)(vt + (di * 16 + l16) * 64 + csv * 8);
                acc_o[di] = __builtin_amdgcn_mfma_f32_16x16x32_bf16(vf, pf, acc_o[di], 0, 0, 0);
            }
        }
    }
    // ---- epilogue: register-direct stores, no LDS reuse, no barrier ----
    if (qb < 4) {
        // single chunk: normalize in fp32, one RNE round, write attnb directly.
        float inv = 1.0f / l_run;
        long gq = (long)(qrow + l16) * D_MODEL + h * DH;
#pragma unroll
        for (int di = 0; di < 8; di++) {
            uint2 pk;
            pk.x = (unsigned)f2b(acc_o[di][0] * inv) | ((unsigned)f2b(acc_o[di][1] * inv) << 16);
            pk.y = (unsigned)f2b(acc_o[di][2] * inv) | ((unsigned)f2b(acc_o[di][3] * inv) << 16);
            *(uint2*)(attnb + gq + di * 16 + quad * 4) = pk;
        }
    } else {
        // multi-chunk: fp32 partials (no intermediate bf16 rounding).
        long ob = (part_row(ch, h, qrow) + l16) * 128 + quad * 4;
#pragma unroll
        for (int di = 0; di < 8; di++)
            *(floatx4*)(Opf + ob + di * 16) = acc_o[di];
        if (lane < 16) {
            float2 v; v.x = m_run; v.y = l_run;
            *(float2*)(mlbuf + part_row(ch, h, qrow + lane) * 2) = v;
        }
    }
}

// ---------------- combine split-KV fp32 partials (log2 domain); rows t>=512 only ----------------
__global__ __launch_bounds__(256) void reduce_kernel(
    const float* __restrict__ Opf, const float* __restrict__ ml, u16* __restrict__ attnb)
{
    int idx = blockIdx.x * 4 + (threadIdx.x >> 6);   // one wave per (h, t)
    int h = idx / 1536;
    int t = 512 + (idx - h * 1536);
    int nch = (t >> 9) + 1;                          // 2..4
    int lane = threadIdx.x & 63;
    float mv[4], lv[4];
    float m = -3e38f;
    for (int c = 0; c < nch; c++) {
        float2 v = *(const float2*)(ml + part_row(c, h, t) * 2);
        mv[c] = v.x; lv[c] = v.y;
        m = fmaxf(m, v.x);
    }
    float lsum = 0.f, o0 = 0.f, o1 = 0.f;
    for (int c = 0; c < nch; c++) {
        float w = exp2f(mv[c] - m);
        lsum += w * lv[c];
        float2 pv = *(const float2*)(Opf + part_row(c, h, t) * 128 + lane * 2);
        o0 += w * pv.x;
        o1 += w * pv.y;
    }
    float inv = 1.0f / lsum;
    unsigned pk = (unsigned)f2b(o0 * inv) | ((unsigned)f2b(o1 * inv) << 16);
    *(unsigned*)(attnb + (long)t * D_MODEL + h * DH + lane * 2) = pk;
}

extern "C" void kernel_launch(void* const* d_in, const int* in_sizes, int n_in,
                              void* d_out, int out_size, void* d_ws, size_t ws_size,
                              hipStream_t stream) {
    const int*   positions = (const int*)d_in[0];
    const float* hidden    = (const float*)d_in[1];
    const float* Wqkv      = (const float*)d_in[2];
    const float* bqkv      = (const float*)d_in[3];
    const float* Wo        = (const float*)d_in[4];
    float* out = (float*)d_out;

    char* w = (char*)d_ws;
    u16*   woT    = (u16*)(w);                      // 25.7MB, persist
    u16*   hid_b  = (u16*)(w + 26214400);           // dead after gemm1
    u16*   wqkvT  = (u16*)(w + 41943040);           // dead after gemm1
    float* qkv32  = (float*)(w + 75497472);         // dead after rope
    u16*   Qb     = (u16*)(w + 115343360);          // persist through attn
    u16*   Kb     = (u16*)(w + 130023424);          // persist through attn
    u16*   VbT    = (u16*)(w + 132120576);          // persist through attn (ends 128MiB)
    u16*   attnb  = (u16*)(w + 26214400);           // reuse hid_b region
    float* Opf    = (float*)(w + 41943040);         // fp32 partials, 66,060,288B (compact)
    float* mlbuf  = (float*)(w + 108003328);        // (m,l) compact, 1,032,192B -> ends 109MB

    int nh = T_SEQ * D_MODEL;
    cvt_kernel<<<nh / 1024, 256, 0, stream>>>(hidden, hid_b, nh);
    transpose_cvt<<<dim3(NQKV / 32, D_MODEL / 32), dim3(32, 8), 0, stream>>>(Wqkv, wqkvT, D_MODEL, NQKV);
    transpose_cvt<<<dim3(D_MODEL / 32, D_MODEL / 32), dim3(32, 8), 0, stream>>>(Wo, woT, D_MODEL, D_MODEL);
    gemm_bt<<<dim3(NQKV / 128, T_SEQ / 128), 256, 0, stream>>>(hid_b, wqkvT, qkv32, bqkv,
                                                              T_SEQ, NQKV, D_MODEL);
    rope_split<<<dim3(T_SEQ, HQ + 2 * HKV), 64, 0, stream>>>(qkv32, positions, Qb, Kb, VbT);
    attn_kernel<<<dim3(40, HQ), 512, 0, stream>>>(Qb, Kb, VbT, Opf, mlbuf, attnb);
    reduce_kernel<<<HQ * 1536 / 4, 256, 0, stream>>>(Opf, mlbuf, attnb);
    gemm_bt<<<dim3(D_MODEL / 128, T_SEQ / 128), 256, 0, stream>>>(attnb, woT, out, nullptr,
                                                                 T_SEQ, D_MODEL, D_MODEL);
}

// Round 7
// 458.995 us; speedup vs baseline: 1.0447x; 1.0447x over previous
//
#include <hip/hip_runtime.h>
#include <hip/hip_bf16.h>

// Qwen2 attention block: qkv = hs@Wqkv+b; rope(q,k); causal GQA attention; out = attn@Wo
// T=2048 D=3584 HQ=28 HKV=4 DH=128. All matmuls in bf16 MFMA (16x16x32), fp32 accum.
// R4: RNE P-pack, rounded-P denom, fp32 split-KV partials -> absmax 0.031.
// R6: 1-barrier dbuf skeleton (determinism-proven). R7 FAILED: no staging (VGPR-bound).
// R8: K+V staged dbuf attn, 128q x 8 waves -> 473us; attn <=110, gemms 111 ea.
// R9 FAILED (479): BK=64 -> 64KB LDS -> 1 blk/CU (Occ 12.4%); XCD remap -> FETCH +83%.
//     (T2 swizzle itself verified: bank conflicts 8.26M -> 0.) Reverted gemm to R8.
// R10: attack the ~140us of small-kernel time: fused prep (cvt+2 transposes, 1 launch,
//     float4 reads + uint2 bf16 writes), rope V-path LDS-staged uint4 writes (was 2B
//     scatter @4KB stride). Per-element math identical -> absmax unchanged.

#define T_SEQ 2048
#define D_MODEL 3584
#define HQ 28
#define HKV 4
#define GQA 7
#define DH 128
#define NQKV 4608   // (HQ+2*HKV)*DH
#define KVD 512     // HKV*DH

typedef unsigned short u16;
typedef __attribute__((ext_vector_type(8))) short short8;   // 8 bf16 (4 VGPRs)
typedef __attribute__((ext_vector_type(4))) float floatx4;

__device__ __forceinline__ u16 f2b(float x) {               // fp32 -> bf16 RNE
    unsigned u = __float_as_uint(x);
    return (u16)((u + 0x7fffu + ((u >> 16) & 1u)) >> 16);
}
__device__ __forceinline__ float b2f(u16 x) {
    return __uint_as_float((unsigned)x << 16);
}
__device__ __forceinline__ void gl_lds16(const u16* g, u16* l) {
    // async global->LDS, 16B/lane; LDS dest = wave-uniform base + lane*16
    __builtin_amdgcn_global_load_lds((const __attribute__((address_space(1))) void*)g,
                                     (__attribute__((address_space(3))) void*)l, 16, 0, 0);
}

// Compact split-KV partial row index. Chunk c covers kv [512c,512c+512); partials are
// only needed for rows with >=2 chunks: t >= 512*max(c,1). Row counts {1536,1536,1024,512}.
__device__ __forceinline__ long part_row(int c, int h, int t) {
    int tmin = (c == 0) ? 512 : (c << 9);
    int rows = 2048 - tmin;
    int rb = (c <= 1) ? (c * 1536) : (c == 2 ? 3072 : 4096);   // row prefix sum
    return (long)rb * HQ + (long)h * rows + (t - tmin);
}

// ---------------- fused prep: cvt(hidden) + transpose_cvt(Wqkv) + transpose_cvt(Wo) ----------------
// blocks [0,7168): hidden fp32->bf16 (float4 in, uint2 out).
// blocks [7168,11200): Wqkv (3584x4608) -> wqkvT (4608x3584) bf16.
// blocks [11200,14336): Wo (3584x3584) -> woT bf16.
// 64x64 transpose tiles: float4 coalesced reads, LDS stage, uint2 coalesced writes.
__global__ __launch_bounds__(256) void prep_kernel(
    const float* __restrict__ hidden, const float* __restrict__ Wqkv, const float* __restrict__ Wo,
    u16* __restrict__ hid_b, u16* __restrict__ wqkvT, u16* __restrict__ woT)
{
    int bx = blockIdx.x;
    if (bx < 7168) {                                   // 7168*1024 = 2048*3584 exactly
        int i = bx * 1024 + threadIdx.x * 4;
        float4 v = *(const float4*)(hidden + i);
        uint2 pk;
        pk.x = (unsigned)f2b(v.x) | ((unsigned)f2b(v.y) << 16);
        pk.y = (unsigned)f2b(v.z) | ((unsigned)f2b(v.w) << 16);
        *(uint2*)(hid_b + i) = pk;
        return;
    }
    const float* in; u16* out; int C, tid2;
    if (bx < 11200) { in = Wqkv; out = wqkvT; C = NQKV;    tid2 = bx - 7168;  }
    else            { in = Wo;   out = woT;   C = D_MODEL; tid2 = bx - 11200; }
    const int R = D_MODEL;
    int tC = C >> 6;
    int c0 = (tid2 % tC) << 6, r0 = (tid2 / tC) << 6;
    __shared__ __align__(16) u16 tile[64][68];         // row stride 136B (17x8 -> b64-aligned)
    int l = threadIdx.x & 15, g = threadIdx.x >> 4;    // l: col-quad, g: row group 0..15
#pragma unroll
    for (int i = 0; i < 4; i++) {
        int r = g + 16 * i;
        float4 v = *(const float4*)(in + (long)(r0 + r) * C + c0 + l * 4);
        uint2 pk;
        pk.x = (unsigned)f2b(v.x) | ((unsigned)f2b(v.y) << 16);
        pk.y = (unsigned)f2b(v.z) | ((unsigned)f2b(v.w) << 16);
        *(uint2*)&tile[r][l * 4] = pk;                 // 8B LDS write, aligned
    }
    __syncthreads();
#pragma unroll
    for (int i = 0; i < 4; i++) {
        int cc = g + 16 * i;                           // out row = c0+cc
        u16 e0 = tile[l * 4 + 0][cc], e1 = tile[l * 4 + 1][cc];
        u16 e2 = tile[l * 4 + 2][cc], e3 = tile[l * 4 + 3][cc];
        uint2 pk;
        pk.x = (unsigned)e0 | ((unsigned)e1 << 16);
        pk.y = (unsigned)e2 | ((unsigned)e3 << 16);
        *(uint2*)(out + (long)(c0 + cc) * R + r0 + l * 4) = pk;
    }
}

// ---------------- bf16 GEMM: C = A(MxK) * Bt(NxK)^T + bias, fp32 out ----------------
// 128x128 tile, BK=32, global_load_lds staging, double-buffered, 1 barrier/iter. (R8-exact)
__global__ __launch_bounds__(256) void gemm_bt(
    const u16* __restrict__ A, const u16* __restrict__ Bt,
    float* __restrict__ C, const float* __restrict__ bias,
    int M, int N, int K)
{
    __shared__ __align__(16) u16 As[2][128 * 32];
    __shared__ __align__(16) u16 Bs[2][128 * 32];
    const int tid = threadIdx.x;
    const int lane = tid & 63, wave = tid >> 6;
    const int quad = lane >> 4, l16 = lane & 15;
    const int wm = (wave >> 1) * 64, wn = (wave & 1) * 64;
    const int m0 = blockIdx.y * 128, n0 = blockIdx.x * 128;

    floatx4 acc[4][4] = {};

    auto stage = [&](int k0, int b) {
#pragma unroll
        for (int j = 0; j < 2; j++) {
            int r = wave * 32 + j * 16 + (lane >> 2);
            const u16* ga = A + (long)(m0 + r) * K + k0 + (lane & 3) * 8;
            const u16* gb = Bt + (long)(n0 + r) * K + k0 + (lane & 3) * 8;
            gl_lds16(ga, &As[b][(wave * 32 + j * 16) * 32]);
            gl_lds16(gb, &Bs[b][(wave * 32 + j * 16) * 32]);
        }
    };

    stage(0, 0);
    int it = 0;
    for (int k0 = 0; k0 < K; k0 += 32, it++) {
        int b = it & 1;
        __syncthreads();
        if (k0 + 32 < K) stage(k0 + 32, b ^ 1);
        short8 af[4], bfr[4];
#pragma unroll
        for (int i = 0; i < 4; i++)
            af[i] = *(const short8*)(&As[b][0] + (wm + i * 16 + l16) * 32 + quad * 8);
#pragma unroll
        for (int i = 0; i < 4; i++)
            bfr[i] = *(const short8*)(&Bs[b][0] + (wn + i * 16 + l16) * 32 + quad * 8);
#pragma unroll
        for (int mi = 0; mi < 4; mi++)
#pragma unroll
            for (int ni = 0; ni < 4; ni++)
                acc[mi][ni] = __builtin_amdgcn_mfma_f32_16x16x32_bf16(af[mi], bfr[ni], acc[mi][ni], 0, 0, 0);
    }

#pragma unroll
    for (int mi = 0; mi < 4; mi++) {
        int row = m0 + wm + mi * 16 + quad * 4;
#pragma unroll
        for (int ni = 0; ni < 4; ni++) {
            int col = n0 + wn + ni * 16 + l16;
            float b = bias ? bias[col] : 0.0f;
#pragma unroll
            for (int r = 0; r < 4; r++)
                C[(long)(row + r) * N + col] = acc[mi][ni][r] + b;
        }
    }
}

// ---------------- RoPE + split; Q pre-scaled by (1/sqrt(DH))*log2(e) for exp2 softmax ----------------
// 8 timesteps per block (one per wave). Q/K writes coalesced as before; V staged via LDS
// and written as uint4 rows of VbT (16B) instead of 2B scatter at 4KB stride.
__global__ __launch_bounds__(512) void rope_split(
    const float* __restrict__ qkv, const int* __restrict__ pos,
    u16* __restrict__ Qb, u16* __restrict__ Kb, u16* __restrict__ VbT)
{
    __shared__ __align__(16) u16 vt[128][8];
    int h = blockIdx.y;
    int w = threadIdx.x >> 6, j = threadIdx.x & 63;
    int t = blockIdx.x * 8 + w;
    const float* row = qkv + (long)t * NQKV + h * DH;
    if (h < HQ + HKV) {
        float x1 = row[j], x2 = row[j + 64];
        float inv = exp2f(-0.311430758889f * (float)j);   // theta^(-j/64)
        float ang = (float)pos[t] * inv;
        float c = cosf(ang), s = sinf(ang);
        float o1 = x1 * c - x2 * s;
        float o2 = x2 * c + x1 * s;
        if (h < HQ) {
            const float scale = 0.08838834764831845f * 1.4426950408889634f;  // 1/sqrt(128)*log2e
            u16* o = Qb + (long)t * D_MODEL + h * DH;
            o[j] = f2b(o1 * scale); o[j + 64] = f2b(o2 * scale);
        } else {
            u16* o = Kb + (long)t * KVD + (h - HQ) * DH;
            o[j] = f2b(o1); o[j + 64] = f2b(o2);
        }
    } else {
        int hv = h - HQ - HKV;
        vt[j][w]      = f2b(row[j]);
        vt[j + 64][w] = f2b(row[j + 64]);
        __syncthreads();                   // block-uniform branch (h)
        int d = threadIdx.x;
        if (d < 128) {
            uint4 v = *(const uint4*)&vt[d][0];
            *(uint4*)(VbT + (long)(hv * DH + d) * T_SEQ + blockIdx.x * 8) = v;
        }
    }
}

// ---------------- flash attention, split-KV, S^T form. Block = 128 q x 512 kv chunk. ----------------
// R8: K+V double-buffered via global_load_lds (no VGPR cost), ONE barrier/iter — exact
// gemm_bt skeleton (determinism-proven). 8 waves/block, 80KB LDS -> 2 blocks/CU.
__global__ __launch_bounds__(512, 4) void attn_kernel(
    const u16* __restrict__ Qb, const u16* __restrict__ Kb, const u16* __restrict__ VbT,
    float* __restrict__ Opf, float* __restrict__ mlbuf, u16* __restrict__ attnb)
{
    __shared__ __align__(16) u16 smem[40960];  // Kt[2][64*128] | Vt[2][128*64] | Ps[8][16*64] = 80KB
    u16* Ps = smem + 32768;
    // decode (qb, chunk) for 128-row q tiles: tier g=qb>>2 has g+1 chunks of 512 kv
    int bx = blockIdx.x, qb, ch;
    if (bx < 4)       { qb = bx;               ch = 0; }
    else if (bx < 12) { int j = bx - 4;  qb = 4  + (j >> 1); ch = j & 1; }
    else if (bx < 24) { int j = bx - 12; qb = 8  + j / 3;    ch = j % 3; }
    else              { int j = bx - 24; qb = 12 + (j >> 2); ch = j & 3; }
    const int h = blockIdx.y;
    const int kvh = h / GQA;
    const int q0 = qb * 128;
    const int c_lo = ch * 512;
    const int c_hi = min(c_lo + 512, q0 + 128);
    const int n_it = (c_hi - c_lo) >> 6;
    const int tid = threadIdx.x;
    const int wave = tid >> 6, lane = tid & 63;   // wave 0..7
    const int quad = lane >> 4, l16 = lane & 15;
    const int h7 = l16 & 7;
    const int qrow = q0 + wave * 16;

    auto stageK = [&](int itx, int b) {           // Kt[b]: [kv=64][d=128], XOR-swizzled 16B blocks
        int c0 = c_lo + (itx << 6);
        u16* kt = smem + b * 8192;
#pragma unroll
        for (int j = 0; j < 2; j++) {             // 4 rows x 256B per instr
            int row = wave * 8 + j * 4 + (lane >> 4);
            int gcb = ((lane & 15) & 8) | (((lane & 15) & 7) ^ (row & 7));
            gl_lds16(Kb + (long)(c0 + row) * KVD + kvh * DH + gcb * 8,
                     kt + (wave * 8 + j * 4) * 128);
        }
    };
    auto stageV = [&](int itx, int b) {           // Vt[b]: [d=128][t=64], XOR-swizzled
        int c0 = c_lo + (itx << 6);
        u16* vt = smem + 16384 + b * 8192;
#pragma unroll
        for (int j = 0; j < 2; j++) {             // 8 rows x 128B per instr
            int row = wave * 16 + j * 8 + (lane >> 3);
            int gcb = (lane & 7) ^ (row & 7);
            gl_lds16(VbT + (long)(kvh * DH + row) * T_SEQ + c0 + gcb * 8,
                     vt + (wave * 16 + j * 8) * 64);
        }
    };

    // Q as B-operand: B[n=q=l16][k=d], b128 loads
    short8 qf[4];
    const u16* qptr = Qb + (long)(qrow + l16) * D_MODEL + h * DH;
#pragma unroll
    for (int kc = 0; kc < 4; kc++)
        qf[kc] = *(const short8*)(qptr + kc * 32 + quad * 8);

    floatx4 acc_o[8] = {};                 // O^T[d = di*16+quad*4+r][q = l16]
    float m_run = -3e38f, l_run = 0.f;     // per-lane: one q row (log2 domain)
    u16* pw = Ps + wave * (16 * 64);

    stageK(0, 0);
    stageV(0, 0);

    for (int itx = 0; itx < n_it; itx++) {
        int c0 = c_lo + (itx << 6);
        int b = itx & 1;
        __syncthreads();                   // Kt[b],Vt[b] staged (own-wave DMA drained here)
        if (itx + 1 < n_it) { stageK(itx + 1, b ^ 1); stageV(itx + 1, b ^ 1); }
        u16* kt = smem + b * 8192;
        u16* vt = smem + 16384 + b * 8192;
        // ---- S^T = K Q^T: lane owns q=l16, kv = mi*16+quad*4+r ----
        floatx4 s[4] = {};
#pragma unroll
        for (int kc = 0; kc < 4; kc++) {
            short8 kf[4];
            int cs = (((kc * 4 + quad) & 8)) | (((kc * 4 + quad) & 7) ^ h7);
#pragma unroll
            for (int mi = 0; mi < 4; mi++)
                kf[mi] = *(const short8*)(kt + (mi * 16 + l16) * 128 + cs * 8);
#pragma unroll
            for (int mi = 0; mi < 4; mi++)
                s[mi] = __builtin_amdgcn_mfma_f32_16x16x32_bf16(kf[mi], qf[kc], s[mi], 0, 0, 0);
        }
        // ---- causal mask (wave-uniform branch; only diagonal-crossing tiles) ----
        if (c0 + 63 > qrow) {
            int qg = qrow + l16;
#pragma unroll
            for (int mi = 0; mi < 4; mi++)
#pragma unroll
                for (int r = 0; r < 4; r++)
                    if (c0 + mi * 16 + quad * 4 + r > qg) s[mi][r] = -1e30f;
        }
        // ---- per-lane online softmax (in-lane 16 + 2 cross-quad shuffles) ----
        float tm = s[0][0];
#pragma unroll
        for (int mi = 0; mi < 4; mi++)
#pragma unroll
            for (int r = 0; r < 4; r++) tm = fmaxf(tm, s[mi][r]);
        tm = fmaxf(tm, __shfl_xor(tm, 16));
        tm = fmaxf(tm, __shfl_xor(tm, 32));
        float nm = fmaxf(m_run, tm);
        float alpha = exp2f(m_run - nm);
        m_run = nm;
#pragma unroll
        for (int mi = 0; mi < 4; mi++)
#pragma unroll
            for (int r = 0; r < 4; r++)
                s[mi][r] = exp2f(s[mi][r] - nm);
        // ---- pack P to bf16 with RNE; denominator from the ROUNDED values so the
        //      softmax normalization is exact w.r.t. what the PV MFMA actually sums ----
        float rs = 0.f;
#pragma unroll
        for (int mi = 0; mi < 4; mi++) {
            int cb = (mi * 2 + (quad >> 1)) ^ h7;
#pragma unroll
            for (int c = 0; c < 2; c++) {
                u16 ra = f2b(s[mi][2 * c]), rb2 = f2b(s[mi][2 * c + 1]);
                rs += b2f(ra) + b2f(rb2);
                *(unsigned*)(pw + l16 * 64 + cb * 8 + (quad & 1) * 4 + c * 2) =
                    (unsigned)ra | ((unsigned)rb2 << 16);
            }
        }
        rs += __shfl_xor(rs, 16);
        rs += __shfl_xor(rs, 32);
        l_run = l_run * alpha + rs;
        asm volatile("" ::: "memory");     // compiler fence: Ps stores before Ps loads (same wave)
#pragma unroll
        for (int di = 0; di < 8; di++)
#pragma unroll
            for (int r = 0; r < 4; r++)
                acc_o[di][r] *= alpha;
        // ---- O^T += V^T P: A=V^T from Vt[b], B=P from wave-private Ps ----
#pragma unroll
        for (int kc = 0; kc < 2; kc++) {
            uint4 pv = *(const uint4*)(pw + l16 * 64 + (((kc * 4 + quad) ^ h7) << 3));
            short8 pf = __builtin_bit_cast(short8, pv);
            int csv = (kc * 4 + quad) ^ h7;
#pragma unroll
            for (int di = 0; di < 8; di++) {
                short8 vf = *(const short8*)(vt + (di * 16 + l16) * 64 + csv * 8);
                acc_o[di] = __builtin_amdgcn_mfma_f32_16x16x32_bf16(vf, pf, acc_o[di], 0, 0, 0);
            }
        }
    }
    // ---- epilogue: register-direct stores, no LDS reuse, no barrier ----
    if (qb < 4) {
        // single chunk: normalize in fp32, one RNE round, write attnb directly.
        float inv = 1.0f / l_run;
        long gq = (long)(qrow + l16) * D_MODEL + h * DH;
#pragma unroll
        for (int di = 0; di < 8; di++) {
            uint2 pk;
            pk.x = (unsigned)f2b(acc_o[di][0] * inv) | ((unsigned)f2b(acc_o[di][1] * inv) << 16);
            pk.y = (unsigned)f2b(acc_o[di][2] * inv) | ((unsigned)f2b(acc_o[di][3] * inv) << 16);
            *(uint2*)(attnb + gq + di * 16 + quad * 4) = pk;
        }
    } else {
        // multi-chunk: fp32 partials (no intermediate bf16 rounding).
        long ob = (part_row(ch, h, qrow) + l16) * 128 + quad * 4;
#pragma unroll
        for (int di = 0; di < 8; di++)
            *(floatx4*)(Opf + ob + di * 16) = acc_o[di];
        if (lane < 16) {
            float2 v; v.x = m_run; v.y = l_run;
            *(float2*)(mlbuf + part_row(ch, h, qrow + lane) * 2) = v;
        }
    }
}

// ---------------- combine split-KV fp32 partials (log2 domain); rows t>=512 only ----------------
__global__ __launch_bounds__(256) void reduce_kernel(
    const float* __restrict__ Opf, const float* __restrict__ ml, u16* __restrict__ attnb)
{
    int idx = blockIdx.x * 4 + (threadIdx.x >> 6);   // one wave per (h, t)
    int h = idx / 1536;
    int t = 512 + (idx - h * 1536);
    int nch = (t >> 9) + 1;                          // 2..4
    int lane = threadIdx.x & 63;
    float mv[4], lv[4];
    float m = -3e38f;
    for (int c = 0; c < nch; c++) {
        float2 v = *(const float2*)(ml + part_row(c, h, t) * 2);
        mv[c] = v.x; lv[c] = v.y;
        m = fmaxf(m, v.x);
    }
    float lsum = 0.f, o0 = 0.f, o1 = 0.f;
    for (int c = 0; c < nch; c++) {
        float w = exp2f(mv[c] - m);
        lsum += w * lv[c];
        float2 pv = *(const float2*)(Opf + part_row(c, h, t) * 128 + lane * 2);
        o0 += w * pv.x;
        o1 += w * pv.y;
    }
    float inv = 1.0f / lsum;
    unsigned pk = (unsigned)f2b(o0 * inv) | ((unsigned)f2b(o1 * inv) << 16);
    *(unsigned*)(attnb + (long)t * D_MODEL + h * DH + lane * 2) = pk;
}

extern "C" void kernel_launch(void* const* d_in, const int* in_sizes, int n_in,
                              void* d_out, int out_size, void* d_ws, size_t ws_size,
                              hipStream_t stream) {
    const int*   positions = (const int*)d_in[0];
    const float* hidden    = (const float*)d_in[1];
    const float* Wqkv      = (const float*)d_in[2];
    const float* bqkv      = (const float*)d_in[3];
    const float* Wo        = (const float*)d_in[4];
    float* out = (float*)d_out;

    char* w = (char*)d_ws;
    u16*   woT    = (u16*)(w);                      // 25.7MB, persist
    u16*   hid_b  = (u16*)(w + 26214400);           // dead after gemm1
    u16*   wqkvT  = (u16*)(w + 41943040);           // dead after gemm1
    float* qkv32  = (float*)(w + 75497472);         // dead after rope
    u16*   Qb     = (u16*)(w + 115343360);          // persist through attn
    u16*   Kb     = (u16*)(w + 130023424);          // persist through attn
    u16*   VbT    = (u16*)(w + 132120576);          // persist through attn (ends 128MiB)
    u16*   attnb  = (u16*)(w + 26214400);           // reuse hid_b region
    float* Opf    = (float*)(w + 41943040);         // fp32 partials, 66,060,288B (compact)
    float* mlbuf  = (float*)(w + 108003328);        // (m,l) compact, 1,032,192B -> ends 109MB

    prep_kernel<<<14336, 256, 0, stream>>>(hidden, Wqkv, Wo, hid_b, wqkvT, woT);
    gemm_bt<<<dim3(NQKV / 128, T_SEQ / 128), 256, 0, stream>>>(hid_b, wqkvT, qkv32, bqkv,
                                                              T_SEQ, NQKV, D_MODEL);
    rope_split<<<dim3(T_SEQ / 8, HQ + 2 * HKV), 512, 0, stream>>>(qkv32, positions, Qb, Kb, VbT);
    attn_kernel<<<dim3(40, HQ), 512, 0, stream>>>(Qb, Kb, VbT, Opf, mlbuf, attnb);
    reduce_kernel<<<HQ * 1536 / 4, 256, 0, stream>>>(Opf, mlbuf, attnb);
    gemm_bt<<<dim3(D_MODEL / 128, T_SEQ / 128), 256, 0, stream>>>(attnb, woT, out, nullptr,
                                                                 T_SEQ, D_MODEL, D_MODEL);
}